// Round 5
// baseline (537.204 us; speedup 1.0000x reference)
//
#include <hip/hip_runtime.h>
#include <hip/hip_bf16.h>
#include <hip/hip_cooperative_groups.h>

namespace cg = cooperative_groups;

#define N_NODES 50000
#define N_EDGES 600000
#define HID     128
#define NG      500
#define NB_SCAN 196   // ceil(50000/256)
#define HSTP    65    // padded LDS leading dim
#define PREP_BLOCKS 512

// ---------------- Fused prep: CSR build + dinv + s1raw + w3lin (cooperative) ----------------

__global__ __launch_bounds__(256) void k_prep(const int* __restrict__ esrc,
                                              const int* __restrict__ edst,
                                              const float* __restrict__ x,
                                              const float* __restrict__ W3,
                                              const float* __restrict__ Wlin,
                                              const float* __restrict__ b3,
                                              const float* __restrict__ blin,
                                              int* __restrict__ cnt,
                                              int* __restrict__ bsum,
                                              int* __restrict__ rowptr,
                                              float* __restrict__ dinv,
                                              float* __restrict__ s1raw,
                                              int* __restrict__ csr,
                                              float* __restrict__ w3buf) {
    cg::grid_group grid = cg::this_grid();
    __shared__ int s[256];
    const int tid = blockIdx.x * 256 + threadIdx.x;
    const int nth = PREP_BLOCKS * 256;   // 131072

    // phase 1: zero cnt + s1raw; block 0 computes w3lin = W3@Wlin and consts
    for (int i = tid; i < N_NODES; i += nth) { cnt[i] = 0; s1raw[i] = 0.f; }
    if (blockIdx.x == 0) {
        int t = threadIdx.x;
        int k = t >> 1, j = t & 1;
        float acc = 0.f;
        for (int m = 0; m < 128; m++) acc += W3[k * 128 + m] * Wlin[m * 2 + j];
        w3buf[k * 2 + j] = acc;
        if (t < 2) {
            float c = 0.f;
            for (int m = 0; m < 128; m++) c += b3[m] * Wlin[m * 2 + t];
            w3buf[256 + t] = c + blin[t];   // added to every non-empty graph
            w3buf[258 + t] = blin[t];       // empty-graph fallback
        }
    }
    grid.sync();

    // phase 2: degree count
    for (int e = tid; e < N_EDGES; e += nth) atomicAdd(&cnt[edst[e]], 1);
    grid.sync();

    // phase 3a: per-256-chunk local scan (blocks 0..NB_SCAN-1), chunk totals -> bsum
    if (blockIdx.x < NB_SCAN) {
        int i = blockIdx.x * 256 + threadIdx.x;
        int c = (i < N_NODES) ? cnt[i] : 0;
        s[threadIdx.x] = c;
        __syncthreads();
        for (int o = 1; o < 256; o <<= 1) {
            int v = (threadIdx.x >= o) ? s[threadIdx.x - o] : 0;
            __syncthreads();
            s[threadIdx.x] += v;
            __syncthreads();
        }
        if (threadIdx.x == 255) bsum[blockIdx.x] = s[255];
        if (i < N_NODES) rowptr[i] = s[threadIdx.x] - c;   // local exclusive prefix
    }
    grid.sync();

    // phase 3b: scan bsum (196 entries) with one wave of block 0
    if (blockIdx.x == 0 && threadIdx.x < 64) {
        int lane = threadIdx.x;
        int v[4]; int base = lane * 4;
        for (int j = 0; j < 4; j++) v[j] = (base + j < NB_SCAN) ? bsum[base + j] : 0;
        int tot = v[0] + v[1] + v[2] + v[3];
        int inc = tot;
        for (int o = 1; o < 64; o <<= 1) {
            int u = __shfl_up(inc, o);
            if (lane >= o) inc += u;
        }
        int run = inc - tot;
        for (int j = 0; j < 4; j++) {
            if (base + j < NB_SCAN) bsum[base + j] = run;
            run += v[j];
        }
    }
    grid.sync();

    // phase 3c: finalize rowptr, dinv; re-zero cnt for fill phase
    for (int i = tid; i < N_NODES; i += nth) {
        int rp = rowptr[i] + bsum[i >> 8];
        rowptr[i] = rp;
        int c = cnt[i];
        dinv[i] = rsqrtf((float)c + 1.0f);
        cnt[i] = 0;
        if (i == N_NODES - 1) rowptr[N_NODES] = rp + c;
    }
    grid.sync();

    // phase 4: CSR fill + layer-1 scalar aggregate (atomic)
    for (int e = tid; e < N_EDGES; e += nth) {
        int d = edst[e], sn = esrc[e];
        int pos = atomicAdd(&cnt[d], 1);
        csr[rowptr[d] + pos] = sn;
        atomicAdd(&s1raw[d], x[sn] * dinv[sn]);
    }
}

// ---------------- Fused layer-1 epilogue + layer-2 GEMM ----------------
// O[M,128] = relu(s1 ⊗ W1 + b1) @ W2, with s1 = x*di^2 + s1raw*di built on the fly.

__global__ __launch_bounds__(256) void k_gemm_l2(const float* __restrict__ x,
                                                 const float* __restrict__ dinv,
                                                 const float* __restrict__ s1raw,
                                                 const float* __restrict__ W1,
                                                 const float* __restrict__ b1,
                                                 const float* __restrict__ W2,
                                                 float* __restrict__ O) {
    __shared__ float Ws[128 * 64];       // 32 KB
    __shared__ float HsT[128 * HSTP];    // 33.3 KB, [k][r]
    int t  = threadIdx.x;
    int n0 = blockIdx.y * 64;
    int r0 = blockIdx.x * 64;

    for (int p = 0; p < 8; p++) {
        int elem = t * 4 + p * 1024;
        int k = elem >> 6, cc = elem & 63;
        *(float4*)&Ws[elem] = *(const float4*)&W2[k * 128 + n0 + cc];
    }
    // generate h1 tile transposed: HsT[k][r] = relu(s1[r0+r]*W1[k] + b1[k])
    int lane = t & 63, grp = t >> 6;     // 4 groups x 64 lanes
    int rr = r0 + lane;
    float sv = 0.f;
    if (rr < N_NODES) {
        float di = dinv[rr];
        sv = x[rr] * di * di + s1raw[rr] * di;
    }
    for (int kk = 0; kk < 32; kk++) {
        int k = grp * 32 + kk;
        HsT[k * HSTP + lane] = fmaxf(sv * W1[k] + b1[k], 0.f);
    }
    __syncthreads();

    int col = (t & 15) * 4;
    int row = (t >> 4) * 4;
    float acc[4][4] = {};
    #pragma unroll 4
    for (int k = 0; k < 128; k++) {
        float4 w = *(float4*)&Ws[k * 64 + col];
        float4 h = *(float4*)&HsT[k * HSTP + row];
        acc[0][0] += h.x * w.x; acc[0][1] += h.x * w.y; acc[0][2] += h.x * w.z; acc[0][3] += h.x * w.w;
        acc[1][0] += h.y * w.x; acc[1][1] += h.y * w.y; acc[1][2] += h.y * w.z; acc[1][3] += h.y * w.w;
        acc[2][0] += h.z * w.x; acc[2][1] += h.z * w.y; acc[2][2] += h.z * w.z; acc[2][3] += h.z * w.w;
        acc[3][0] += h.w * w.x; acc[3][1] += h.w * w.y; acc[3][2] += h.w * w.z; acc[3][3] += h.w * w.w;
    }
    for (int r = 0; r < 4; r++) {
        int rrr = r0 + row + r;
        if (rrr < N_NODES) {
            float4 v = {acc[r][0], acc[r][1], acc[r][2], acc[r][3]};
            *(float4*)&O[(size_t)rrr * HID + n0 + col] = v;
        }
    }
}

// ---------------- Fused layer-2 agg + relu + (·w3lin) projection to z[N,2] ----------------

__global__ __launch_bounds__(256) void k_agg_fused(const float* __restrict__ H,
                                                   const int* __restrict__ rowptr,
                                                   const int* __restrict__ csr,
                                                   const float* __restrict__ dinv,
                                                   const float* __restrict__ b2,
                                                   const float* __restrict__ w3buf,
                                                   float* __restrict__ z) {
    int node = blockIdx.x * 8 + (threadIdx.x >> 5);   // grid exact: 6250*8 = 50000
    int c4   = threadIdx.x & 31;
    const float4* H4 = (const float4*)H;
    float di = dinv[node];
    float4 h = H4[(size_t)node * 32 + c4];
    float w0 = di * di;
    float4 acc = {h.x * w0, h.y * w0, h.z * w0, h.w * w0};
    int e0 = rowptr[node], e1 = rowptr[node + 1];
    int e = e0;
    for (; e + 7 < e1; e += 8) {
        int   si[8]; float wi[8]; float4 hi[8];
        #pragma unroll
        for (int j = 0; j < 8; j++) si[j] = csr[e + j];
        #pragma unroll
        for (int j = 0; j < 8; j++) wi[j] = dinv[si[j]] * di;
        #pragma unroll
        for (int j = 0; j < 8; j++) hi[j] = H4[(size_t)si[j] * 32 + c4];
        #pragma unroll
        for (int j = 0; j < 8; j++) {
            acc.x += hi[j].x * wi[j]; acc.y += hi[j].y * wi[j];
            acc.z += hi[j].z * wi[j]; acc.w += hi[j].w * wi[j];
        }
    }
    for (; e + 3 < e1; e += 4) {
        int s0 = csr[e], s1 = csr[e+1], s2 = csr[e+2], s3 = csr[e+3];
        float wa = dinv[s0]*di, wb = dinv[s1]*di, wc = dinv[s2]*di, wd = dinv[s3]*di;
        float4 ha = H4[(size_t)s0*32+c4], hb = H4[(size_t)s1*32+c4];
        float4 hc = H4[(size_t)s2*32+c4], hd = H4[(size_t)s3*32+c4];
        acc.x += ha.x*wa + hb.x*wb + hc.x*wc + hd.x*wd;
        acc.y += ha.y*wa + hb.y*wb + hc.y*wc + hd.y*wd;
        acc.z += ha.z*wa + hb.z*wb + hc.z*wc + hd.z*wd;
        acc.w += ha.w*wa + hb.w*wb + hc.w*wc + hd.w*wd;
    }
    for (; e < e1; e++) {
        int s0 = csr[e];
        float wa = dinv[s0] * di;
        float4 ha = H4[(size_t)s0 * 32 + c4];
        acc.x += ha.x*wa; acc.y += ha.y*wa; acc.z += ha.z*wa; acc.w += ha.w*wa;
    }
    float4 b = ((const float4*)b2)[c4];
    float4 v;
    v.x = fmaxf(acc.x + b.x, 0.f); v.y = fmaxf(acc.y + b.y, 0.f);
    v.z = fmaxf(acc.z + b.z, 0.f); v.w = fmaxf(acc.w + b.w, 0.f);
    float4 wA = *(const float4*)&w3buf[c4 * 8];
    float4 wB = *(const float4*)&w3buf[c4 * 8 + 4];
    float p0 = v.x * wA.x + v.y * wA.z + v.z * wB.x + v.w * wB.z;
    float p1 = v.x * wA.y + v.y * wA.w + v.z * wB.y + v.w * wB.w;
    for (int o = 16; o; o >>= 1) { p0 += __shfl_xor(p0, o); p1 += __shfl_xor(p1, o); }
    if (c4 == 0) { z[node * 2 + 0] = p0; z[node * 2 + 1] = p1; }
}

// ---------------- Layer-3 aggregation on z (2-wide) ----------------

__global__ void k_aggz(const float* __restrict__ z, const int* __restrict__ rowptr,
                       const int* __restrict__ csr, const float* __restrict__ dinv,
                       float* __restrict__ az) {
    int i = blockIdx.x * 256 + threadIdx.x;
    if (i >= N_NODES) return;
    const float2* Z = (const float2*)z;
    float di = dinv[i];
    float2 zi = Z[i];
    float a0 = zi.x * di * di, a1 = zi.y * di * di;
    int e0 = rowptr[i], e1 = rowptr[i + 1];
    int e = e0;
    for (; e + 3 < e1; e += 4) {
        int s0 = csr[e], s1 = csr[e+1], s2 = csr[e+2], s3 = csr[e+3];
        float w0 = dinv[s0]*di, w1 = dinv[s1]*di, w2 = dinv[s2]*di, w3 = dinv[s3]*di;
        float2 za = Z[s0], zb = Z[s1], zc = Z[s2], zd = Z[s3];
        a0 += za.x*w0 + zb.x*w1 + zc.x*w2 + zd.x*w3;
        a1 += za.y*w0 + zb.y*w1 + zc.y*w2 + zd.y*w3;
    }
    for (; e < e1; e++) {
        int s = csr[e];
        float w = dinv[s] * di;
        float2 za = Z[s];
        a0 += za.x * w; a1 += za.y * w;
    }
    float2 r = {a0, a1};
    ((float2*)az)[i] = r;
}

// ---------------- Final: per-graph mean of az + consts (batch sorted) ----------------

__global__ __launch_bounds__(64) void k_final2(const float* __restrict__ az,
                                               const int* __restrict__ batch,
                                               const float* __restrict__ w3buf,
                                               float* __restrict__ out) {
    int g = blockIdx.x;
    int lane = threadIdx.x;
    int lo = 0, hi = N_NODES;
    while (lo < hi) { int mid = (lo + hi) >> 1; if (batch[mid] < g) lo = mid + 1; else hi = mid; }
    int start = lo;
    hi = N_NODES;
    while (lo < hi) { int mid = (lo + hi) >> 1; if (batch[mid] < g + 1) lo = mid + 1; else hi = mid; }
    int end = lo;
    float a0 = 0.f, a1 = 0.f;
    for (int n = start + lane; n < end; n += 64) {
        float2 v = ((const float2*)az)[n];
        a0 += v.x; a1 += v.y;
    }
    for (int o = 32; o; o >>= 1) { a0 += __shfl_xor(a0, o); a1 += __shfl_xor(a1, o); }
    if (lane == 0) {
        if (end > start) {
            float inv = 1.0f / (float)(end - start);
            out[g * 2 + 0] = a0 * inv + w3buf[256];
            out[g * 2 + 1] = a1 * inv + w3buf[257];
        } else {
            out[g * 2 + 0] = w3buf[258];
            out[g * 2 + 1] = w3buf[259];
        }
    }
}

// ---------------- launch ----------------

extern "C" void kernel_launch(void* const* d_in, const int* in_sizes, int n_in,
                              void* d_out, int out_size, void* d_ws, size_t ws_size,
                              hipStream_t stream) {
    const float* x    = (const float*)d_in[0];
    const float* W1   = (const float*)d_in[1];
    const float* b1   = (const float*)d_in[2];
    const float* W2   = (const float*)d_in[3];
    const float* b2   = (const float*)d_in[4];
    const float* W3   = (const float*)d_in[5];
    const float* b3   = (const float*)d_in[6];
    const float* Wlin = (const float*)d_in[7];
    const float* blin = (const float*)d_in[8];
    const int*   eidx = (const int*)d_in[9];
    const int*   batch= (const int*)d_in[10];
    const int* esrc = eidx;
    const int* edst = eidx + N_EDGES;
    float* out = (float*)d_out;

    char* w = (char*)d_ws;
    size_t off = 0;
    auto alloc = [&](size_t bytes) { size_t o = off; off = (off + bytes + 255) & ~(size_t)255; return o; };
    int*   cnt    = (int*)  (w + alloc(N_NODES * 4));
    int*   rowptr = (int*)  (w + alloc((N_NODES + 1) * 4));
    int*   csr    = (int*)  (w + alloc(N_EDGES * 4));
    float* dinv   = (float*)(w + alloc(N_NODES * 4));
    int*   bsum   = (int*)  (w + alloc(NB_SCAN * 4));
    float* s1raw  = (float*)(w + alloc(N_NODES * 4));
    float* w3buf  = (float*)(w + alloc(260 * 4));
    float* t2     = (float*)(w + alloc((size_t)N_NODES * HID * 4));
    float* z      = (float*)(w + alloc((size_t)N_NODES * 2 * 4));
    float* az     = (float*)(w + alloc((size_t)N_NODES * 2 * 4));

    // 1: fused prep (cooperative): zero + count + scan + rowptr/dinv + fill + s1raw + w3lin
    void* args[] = {(void*)&esrc, (void*)&edst, (void*)&x, (void*)&W3, (void*)&Wlin,
                    (void*)&b3, (void*)&blin, (void*)&cnt, (void*)&bsum, (void*)&rowptr,
                    (void*)&dinv, (void*)&s1raw, (void*)&csr, (void*)&w3buf};
    hipLaunchCooperativeKernel((void*)k_prep, dim3(PREP_BLOCKS), dim3(256), args, 0, stream);

    // 2: fused layer1-epilogue + layer2 GEMM
    dim3 gg((N_NODES + 63) / 64, 2);
    k_gemm_l2<<<gg, 256, 0, stream>>>(x, dinv, s1raw, W1, b1, W2, t2);

    // 3: fused layer2 agg + relu + projection -> z [N,2]
    k_agg_fused<<<(N_NODES + 7) / 8, 256, 0, stream>>>(t2, rowptr, csr, dinv, b2, w3buf, z);

    // 4: layer3 2-wide aggregation
    k_aggz<<<(N_NODES + 255) / 256, 256, 0, stream>>>(z, rowptr, csr, dinv, az);

    // 5: per-graph mean + consts
    k_final2<<<NG, 64, 0, stream>>>(az, batch, w3buf, out);
}

// Round 6
// 242.033 us; speedup vs baseline: 2.2195x; 2.2195x over previous
//
#include <hip/hip_runtime.h>
#include <hip/hip_bf16.h>

#define N_NODES 50000
#define N_EDGES 600000
#define HID     128
#define NG      500
#define NB_SCAN 196   // ceil(50000/256)
#define EB      2345  // ceil(600000/256) + 1 extra block for w3lin

// ---------------- count degrees (+ last block computes w3lin = W3@Wlin) ----------------

__global__ void k_count(const int* __restrict__ dst, int* __restrict__ cnt,
                        const float* __restrict__ W3, const float* __restrict__ Wlin,
                        const float* __restrict__ b3, const float* __restrict__ blin,
                        float* __restrict__ w3buf) {
    if (blockIdx.x == EB - 1) {
        int t = threadIdx.x;          // 256 threads -> 128x2
        int k = t >> 1, j = t & 1;
        float acc = 0.f;
        for (int m = 0; m < 128; m++) acc += W3[k * 128 + m] * Wlin[m * 2 + j];
        w3buf[k * 2 + j] = acc;
        if (t < 2) {
            float c = 0.f;
            for (int m = 0; m < 128; m++) c += b3[m] * Wlin[m * 2 + t];
            w3buf[256 + t] = c + blin[t];   // const added to every non-empty graph
            w3buf[258 + t] = blin[t];       // empty-graph fallback
        }
        return;
    }
    int e = blockIdx.x * 256 + threadIdx.x;
    if (e < N_EDGES) atomicAdd(&cnt[dst[e]], 1);
}

__global__ void k_blocksum(const int* __restrict__ cnt, int* __restrict__ bsum) {
    __shared__ int s[256];
    int i = blockIdx.x * 256 + threadIdx.x;
    s[threadIdx.x] = (i < N_NODES) ? cnt[i] : 0;
    __syncthreads();
    for (int o = 128; o; o >>= 1) {
        if (threadIdx.x < o) s[threadIdx.x] += s[threadIdx.x + o];
        __syncthreads();
    }
    if (threadIdx.x == 0) bsum[blockIdx.x] = s[0];
}

__global__ void k_scanbsum(int* __restrict__ bsum) {
    int lane = threadIdx.x;            // 64 lanes
    int v[4];
    int base = lane * 4;
    for (int j = 0; j < 4; j++) v[j] = (base + j < NB_SCAN) ? bsum[base + j] : 0;
    int tot = v[0] + v[1] + v[2] + v[3];
    int inc = tot;
    for (int o = 1; o < 64; o <<= 1) {
        int u = __shfl_up(inc, o);
        if (lane >= o) inc += u;
    }
    int run = inc - tot;
    for (int j = 0; j < 4; j++) {
        if (base + j < NB_SCAN) bsum[base + j] = run;
        run += v[j];
    }
}

// finalize rowptr + dinv, re-zero cnt for the fill pass
__global__ void k_rowptr(const int* __restrict__ cnt, const int* __restrict__ bsum,
                         int* __restrict__ rowptr, float* __restrict__ dinv,
                         int* __restrict__ cntz) {
    __shared__ int s[256];
    int i = blockIdx.x * 256 + threadIdx.x;
    int c = (i < N_NODES) ? cnt[i] : 0;
    s[threadIdx.x] = c;
    __syncthreads();
    for (int o = 1; o < 256; o <<= 1) {
        int v = (threadIdx.x >= o) ? s[threadIdx.x - o] : 0;
        __syncthreads();
        s[threadIdx.x] += v;
        __syncthreads();
    }
    if (i < N_NODES) {
        int incl = s[threadIdx.x];
        rowptr[i] = bsum[blockIdx.x] + incl - c;
        dinv[i] = rsqrtf((float)c + 1.0f);
        cntz[i] = 0;
        if (i == N_NODES - 1) rowptr[N_NODES] = bsum[blockIdx.x] + incl;
    }
}

// CSR fill + layer-1 scalar aggregate (atomic)
__global__ void k_fill(const int* __restrict__ src, const int* __restrict__ dst,
                       const int* __restrict__ rowptr, int* __restrict__ cnt,
                       int* __restrict__ csr, const float* __restrict__ x,
                       const float* __restrict__ dinv, float* __restrict__ s1raw) {
    int e = blockIdx.x * 256 + threadIdx.x;
    if (e < N_EDGES) {
        int d = dst[e], sn = src[e];
        int pos = atomicAdd(&cnt[d], 1);
        csr[rowptr[d] + pos] = sn;
        atomicAdd(&s1raw[d], x[sn] * dinv[sn]);
    }
}

// ---------------- Fused: scalar-gather reconstruct g=A·h1, GEMM g@W2, relu+b2, ·w3lin -> z[N,2]
// h1[j][c] = relu(s1[j]*W1[c]+b1[c]) with s1[j] = x[j]*dj^2 + s1raw[j]*dj — reconstructed
// from 12B/edge of scalars instead of gathering 512B/edge rows. t2/h2 never materialized.

__global__ __launch_bounds__(256) void k_gemm_fused(const float* __restrict__ x,
                                                    const float* __restrict__ dinv,
                                                    const float* __restrict__ s1raw,
                                                    const int* __restrict__ rowptr,
                                                    const int* __restrict__ csr,
                                                    const float* __restrict__ W1,
                                                    const float* __restrict__ b1,
                                                    const float* __restrict__ W2,
                                                    const float* __restrict__ b2,
                                                    const float* __restrict__ w3buf,
                                                    float* __restrict__ z) {
    __shared__ float Ws[128 * 64];    // 32 KB
    __shared__ float HsT[128 * 64];   // 32 KB, [k][r] — staging writes are lane-contiguous
    int t = threadIdx.x;
    int r0 = blockIdx.x * 64;
    int lane = t & 63, grp = t >> 6;  // lane = row in tile, grp = channel chunk (4 x 32)

    // per-thread W1/b1 chunk (wave-uniform index -> scalarized loads)
    float w1r[32], b1r[32];
    #pragma unroll
    for (int kk = 0; kk < 32; kk++) { w1r[kk] = W1[grp * 32 + kk]; b1r[kk] = b1[grp * 32 + kk]; }

    // reconstruct-aggregate this row's 32-channel chunk of g = A·h1
    float ga[32];
    #pragma unroll
    for (int kk = 0; kk < 32; kk++) ga[kk] = 0.f;
    int node = r0 + lane;
    if (node < N_NODES) {
        float di = dinv[node];
        float si = x[node] * di * di + s1raw[node] * di;
        float wself = di * di;
        #pragma unroll
        for (int kk = 0; kk < 32; kk++) ga[kk] = fmaxf(si * w1r[kk] + b1r[kk], 0.f) * wself;
        int e0 = rowptr[node], e1 = rowptr[node + 1];
        for (int e = e0; e < e1; e++) {
            int j = csr[e];
            float dj = dinv[j];
            float sj = x[j] * dj * dj + s1raw[j] * dj;
            float wj = dj * di;
            #pragma unroll
            for (int kk = 0; kk < 32; kk++) ga[kk] += fmaxf(sj * w1r[kk] + b1r[kk], 0.f) * wj;
        }
    }
    #pragma unroll
    for (int kk = 0; kk < 32; kk++) HsT[(grp * 32 + kk) * 64 + lane] = ga[kk];

    // stage W2 col-half 0
    for (int p = 0; p < 8; p++) {
        int elem = t * 4 + p * 1024;
        int k = elem >> 6, cc = elem & 63;
        *(float4*)&Ws[elem] = *(const float4*)&W2[k * 128 + cc];
    }
    __syncthreads();

    int col = (t & 15) * 4;
    int row = (t >> 4) * 4;
    float a0[4][4] = {}, a1[4][4] = {};
    #pragma unroll 4
    for (int k = 0; k < 128; k++) {
        float4 w = *(float4*)&Ws[k * 64 + col];
        float4 h = *(float4*)&HsT[k * 64 + row];
        a0[0][0] += h.x * w.x; a0[0][1] += h.x * w.y; a0[0][2] += h.x * w.z; a0[0][3] += h.x * w.w;
        a0[1][0] += h.y * w.x; a0[1][1] += h.y * w.y; a0[1][2] += h.y * w.z; a0[1][3] += h.y * w.w;
        a0[2][0] += h.z * w.x; a0[2][1] += h.z * w.y; a0[2][2] += h.z * w.z; a0[2][3] += h.z * w.w;
        a0[3][0] += h.w * w.x; a0[3][1] += h.w * w.y; a0[3][2] += h.w * w.z; a0[3][3] += h.w * w.w;
    }
    __syncthreads();
    // stage W2 col-half 1, same HsT
    for (int p = 0; p < 8; p++) {
        int elem = t * 4 + p * 1024;
        int k = elem >> 6, cc = elem & 63;
        *(float4*)&Ws[elem] = *(const float4*)&W2[k * 128 + 64 + cc];
    }
    __syncthreads();
    #pragma unroll 4
    for (int k = 0; k < 128; k++) {
        float4 w = *(float4*)&Ws[k * 64 + col];
        float4 h = *(float4*)&HsT[k * 64 + row];
        a1[0][0] += h.x * w.x; a1[0][1] += h.x * w.y; a1[0][2] += h.x * w.z; a1[0][3] += h.x * w.w;
        a1[1][0] += h.y * w.x; a1[1][1] += h.y * w.y; a1[1][2] += h.y * w.z; a1[1][3] += h.y * w.w;
        a1[2][0] += h.z * w.x; a1[2][1] += h.z * w.y; a1[2][2] += h.z * w.z; a1[2][3] += h.z * w.w;
        a1[3][0] += h.w * w.x; a1[3][1] += h.w * w.y; a1[3][2] += h.w * w.z; a1[3][3] += h.w * w.w;
    }

    // epilogue: relu(+b2) then project to 2 outputs; reduce across the 16 lanes of a row group
    float b2a[4], b2b[4], w0a[4], w1a[4], w0b[4], w1b[4];
    #pragma unroll
    for (int c = 0; c < 4; c++) {
        b2a[c] = b2[col + c];        b2b[c] = b2[64 + col + c];
        w0a[c] = w3buf[(col + c) * 2 + 0];      w1a[c] = w3buf[(col + c) * 2 + 1];
        w0b[c] = w3buf[(64 + col + c) * 2 + 0]; w1b[c] = w3buf[(64 + col + c) * 2 + 1];
    }
    #pragma unroll
    for (int r = 0; r < 4; r++) {
        float p0 = 0.f, p1 = 0.f;
        #pragma unroll
        for (int c = 0; c < 4; c++) {
            float v0 = fmaxf(a0[r][c] + b2a[c], 0.f);
            float v1 = fmaxf(a1[r][c] + b2b[c], 0.f);
            p0 += v0 * w0a[c] + v1 * w0b[c];
            p1 += v0 * w1a[c] + v1 * w1b[c];
        }
        for (int o = 1; o < 16; o <<= 1) { p0 += __shfl_xor(p0, o); p1 += __shfl_xor(p1, o); }
        int rg = r0 + row + r;
        if ((t & 15) == 0 && rg < N_NODES) { z[rg * 2 + 0] = p0; z[rg * 2 + 1] = p1; }
    }
}

// ---------------- Layer-3 aggregation on z (2-wide) ----------------

__global__ void k_aggz(const float* __restrict__ z, const int* __restrict__ rowptr,
                       const int* __restrict__ csr, const float* __restrict__ dinv,
                       float* __restrict__ az) {
    int i = blockIdx.x * 256 + threadIdx.x;
    if (i >= N_NODES) return;
    const float2* Z = (const float2*)z;
    float di = dinv[i];
    float2 zi = Z[i];
    float a0 = zi.x * di * di, a1 = zi.y * di * di;
    int e0 = rowptr[i], e1 = rowptr[i + 1];
    int e = e0;
    for (; e + 3 < e1; e += 4) {
        int s0 = csr[e], s1 = csr[e+1], s2 = csr[e+2], s3 = csr[e+3];
        float w0 = dinv[s0]*di, w1 = dinv[s1]*di, w2 = dinv[s2]*di, w3 = dinv[s3]*di;
        float2 za = Z[s0], zb = Z[s1], zc = Z[s2], zd = Z[s3];
        a0 += za.x*w0 + zb.x*w1 + zc.x*w2 + zd.x*w3;
        a1 += za.y*w0 + zb.y*w1 + zc.y*w2 + zd.y*w3;
    }
    for (; e < e1; e++) {
        int s = csr[e];
        float w = dinv[s] * di;
        float2 za = Z[s];
        a0 += za.x * w; a1 += za.y * w;
    }
    float2 r = {a0, a1};
    ((float2*)az)[i] = r;
}

// ---------------- Final: per-graph mean of az + consts (batch sorted) ----------------

__global__ __launch_bounds__(64) void k_final2(const float* __restrict__ az,
                                               const int* __restrict__ batch,
                                               const float* __restrict__ w3buf,
                                               float* __restrict__ out) {
    int g = blockIdx.x;
    int lane = threadIdx.x;
    int lo = 0, hi = N_NODES;
    while (lo < hi) { int mid = (lo + hi) >> 1; if (batch[mid] < g) lo = mid + 1; else hi = mid; }
    int start = lo;
    hi = N_NODES;
    while (lo < hi) { int mid = (lo + hi) >> 1; if (batch[mid] < g + 1) lo = mid + 1; else hi = mid; }
    int end = lo;
    float a0 = 0.f, a1 = 0.f;
    for (int n = start + lane; n < end; n += 64) {
        float2 v = ((const float2*)az)[n];
        a0 += v.x; a1 += v.y;
    }
    for (int o = 32; o; o >>= 1) { a0 += __shfl_xor(a0, o); a1 += __shfl_xor(a1, o); }
    if (lane == 0) {
        if (end > start) {
            float inv = 1.0f / (float)(end - start);
            out[g * 2 + 0] = a0 * inv + w3buf[256];
            out[g * 2 + 1] = a1 * inv + w3buf[257];
        } else {
            out[g * 2 + 0] = w3buf[258];
            out[g * 2 + 1] = w3buf[259];
        }
    }
}

// ---------------- launch ----------------

extern "C" void kernel_launch(void* const* d_in, const int* in_sizes, int n_in,
                              void* d_out, int out_size, void* d_ws, size_t ws_size,
                              hipStream_t stream) {
    const float* x    = (const float*)d_in[0];
    const float* W1   = (const float*)d_in[1];
    const float* b1   = (const float*)d_in[2];
    const float* W2   = (const float*)d_in[3];
    const float* b2   = (const float*)d_in[4];
    const float* W3   = (const float*)d_in[5];
    const float* b3   = (const float*)d_in[6];
    const float* Wlin = (const float*)d_in[7];
    const float* blin = (const float*)d_in[8];
    const int*   eidx = (const int*)d_in[9];
    const int*   batch= (const int*)d_in[10];
    const int* esrc = eidx;
    const int* edst = eidx + N_EDGES;
    float* out = (float*)d_out;

    char* w = (char*)d_ws;
    size_t off = 0;
    auto alloc = [&](size_t bytes) { size_t o = off; off = (off + bytes + 255) & ~(size_t)255; return o; };
    // cnt and s1raw deliberately adjacent -> one memset covers both
    size_t cnt_off = alloc(N_NODES * 4);
    int*   cnt    = (int*)  (w + cnt_off);
    float* s1raw  = (float*)(w + alloc(N_NODES * 4));
    size_t zero_bytes = off - cnt_off;
    int*   rowptr = (int*)  (w + alloc((N_NODES + 1) * 4));
    int*   csr    = (int*)  (w + alloc(N_EDGES * 4));
    float* dinv   = (float*)(w + alloc(N_NODES * 4));
    int*   bsum   = (int*)  (w + alloc(NB_SCAN * 4));
    float* w3buf  = (float*)(w + alloc(260 * 4));
    float* z      = (float*)(w + alloc((size_t)N_NODES * 2 * 4));
    float* az     = (float*)(w + alloc((size_t)N_NODES * 2 * 4));

    // 1: zero cnt + s1raw (single memset)
    hipMemsetAsync(cnt, 0, zero_bytes, stream);
    // 2: degree count + w3lin precompute (extra block)
    k_count<<<EB, 256, 0, stream>>>(edst, cnt, W3, Wlin, b3, blin, w3buf);
    // 3-5: prefix scan -> rowptr, dinv; cnt re-zeroed inside k_rowptr
    k_blocksum<<<NB_SCAN, 256, 0, stream>>>(cnt, bsum);
    k_scanbsum<<<1, 64, 0, stream>>>(bsum);
    k_rowptr<<<NB_SCAN, 256, 0, stream>>>(cnt, bsum, rowptr, dinv, cnt);
    // 6: CSR fill + layer-1 scalar aggregate
    k_fill<<<(N_EDGES + 255) / 256, 256, 0, stream>>>(esrc, edst, rowptr, cnt, csr, x, dinv, s1raw);
    // 7: fused reconstruct-gather + GEMM + relu + projection -> z [N,2]
    k_gemm_fused<<<(N_NODES + 63) / 64, 256, 0, stream>>>(x, dinv, s1raw, rowptr, csr,
                                                          W1, b1, W2, b2, w3buf, z);
    // 8: layer-3 2-wide aggregation
    k_aggz<<<(N_NODES + 255) / 256, 256, 0, stream>>>(z, rowptr, csr, dinv, az);
    // 9: per-graph mean + consts
    k_final2<<<NG, 64, 0, stream>>>(az, batch, w3buf, out);
}